// Round 1
// baseline (93.974 us; speedup 1.0000x reference)
//
#include <hip/hip_runtime.h>
#include <float.h>

// Chamfer distance, B=16, N=2048, D=3, fp32.
// P[b,i,j] = |x_i - y_j|^2 ; cd[b] = mean_j min_i P + mean_i min_j P.

constexpr int B_ = 16;
constexpr int N_ = 2048;
constexpr int THREADS = 256;
constexpr int ICHUNKS = N_ / THREADS;   // 8 query chunks
constexpr int NJC = 4;                  // reference chunks per direction
constexpr int JCHUNK = N_ / NJC;        // 512

// ws layout: float partial[2][B_][NJC][N_]
//   dir 0: query = x, ref = y  -> per-i min over a j-chunk (feeds dr)
//   dir 1: query = y, ref = x  -> per-j min over an i-chunk (feeds dl)

__global__ __launch_bounds__(THREADS)
void cd_min_kernel(const float* __restrict__ x,
                   const float* __restrict__ y,
                   float* __restrict__ partial) {
    const int icjc = blockIdx.x;               // 0 .. ICHUNKS*NJC-1
    const int jc   = icjc & (NJC - 1);
    const int ic   = icjc >> 2;                // log2(NJC)
    const int b    = blockIdx.y;
    const int dir  = blockIdx.z;

    const float* __restrict__ q = dir ? y : x;
    const float* __restrict__ r = dir ? x : y;

    const int i = ic * THREADS + (int)threadIdx.x;
    const float* qp = q + ((size_t)b * N_ + i) * 3;
    const float qx = qp[0];
    const float qy = qp[1];
    const float qz = qp[2];

    // Reference chunk base: uniform across the block -> scalar loads inside loop.
    const float* __restrict__ rp = r + ((size_t)b * N_ + (size_t)jc * JCHUNK) * 3;

    float best = FLT_MAX;
    #pragma unroll 8
    for (int j = 0; j < JCHUNK; ++j) {
        const float dx = qx - rp[3 * j + 0];
        const float dy = qy - rp[3 * j + 1];
        const float dz = qz - rp[3 * j + 2];
        const float d  = dx * dx + dy * dy + dz * dz;
        best = fminf(best, d);
    }

    partial[(((size_t)dir * B_ + b) * NJC + jc) * N_ + i] = best;
}

__global__ __launch_bounds__(THREADS)
void cd_reduce_kernel(const float* __restrict__ partial,
                      float* __restrict__ out) {
    const int b = blockIdx.x;
    const int t = (int)threadIdx.x;

    float sum = 0.0f;
    #pragma unroll
    for (int dir = 0; dir < 2; ++dir) {
        const float* __restrict__ p =
            partial + ((size_t)dir * B_ + b) * NJC * N_;
        for (int i = t; i < N_; i += THREADS) {
            float m = p[i];
            #pragma unroll
            for (int c = 1; c < NJC; ++c)
                m = fminf(m, p[(size_t)c * N_ + i]);
            sum += m;
        }
    }

    // wave64 reduce, then cross-wave via LDS (4 waves).
    #pragma unroll
    for (int o = 32; o > 0; o >>= 1)
        sum += __shfl_down(sum, o, 64);

    __shared__ float red[THREADS / 64];
    if ((t & 63) == 0) red[t >> 6] = sum;
    __syncthreads();
    if (t == 0) {
        float tot = 0.0f;
        #pragma unroll
        for (int w = 0; w < THREADS / 64; ++w) tot += red[w];
        out[b] = tot * (1.0f / (float)N_);
    }
}

extern "C" void kernel_launch(void* const* d_in, const int* in_sizes, int n_in,
                              void* d_out, int out_size, void* d_ws, size_t ws_size,
                              hipStream_t stream) {
    const float* x = (const float*)d_in[0];
    const float* y = (const float*)d_in[1];
    float* out     = (float*)d_out;
    float* partial = (float*)d_ws;   // needs 2*16*4*2048*4 = 1 MiB

    dim3 grid(ICHUNKS * NJC, B_, 2);
    cd_min_kernel<<<grid, dim3(THREADS), 0, stream>>>(x, y, partial);
    cd_reduce_kernel<<<dim3(B_), dim3(THREADS), 0, stream>>>(partial, out);
}

// Round 2
// 72.740 us; speedup vs baseline: 1.2919x; 1.2919x over previous
//
#include <hip/hip_runtime.h>
#include <float.h>

// Chamfer distance, B=16, N=2048, D=3, fp32.
// cd[b] = mean_j min_i |x_i - y_j|^2 + mean_i min_j |x_i - y_j|^2
// Pair form: |q - r|^2 = 2*(0.5|r|^2 - q.r) + |q|^2  -> min over r of the
// affine-monotone inner term, epilogue applies 2*t + |q|^2.

constexpr int B_ = 16;
constexpr int N_ = 2048;
constexpr int THREADS = 256;
constexpr int QPT = 8;                  // queries per thread; THREADS*QPT == N_

// ws layout: float partial[2][B_][NJC][N_]
//   dir 0: query = x, ref = y  (feeds dr);  dir 1: query = y, ref = x (feeds dl)

template <int NJC>
__global__ __launch_bounds__(THREADS)
void cd_min_kernel(const float* __restrict__ x,
                   const float* __restrict__ y,
                   float* __restrict__ partial) {
    constexpr int CHUNK = N_ / NJC;
    const int jc  = blockIdx.x;
    const int b   = blockIdx.y;
    const int dir = blockIdx.z;

    const float* __restrict__ q = dir ? y : x;
    const float* __restrict__ r = dir ? x : y;

    // 8 consecutive query points per thread: 96 contiguous bytes -> x4 loads.
    const int i0 = (int)threadIdx.x * QPT;
    const float* qp = q + ((size_t)b * N_ + i0) * 3;

    float nqx[QPT], nqy[QPT], nqz[QPT], q2[QPT], best[QPT];
    #pragma unroll
    for (int k = 0; k < QPT; ++k) {
        const float a0 = qp[3 * k + 0];
        const float a1 = qp[3 * k + 1];
        const float a2 = qp[3 * k + 2];
        nqx[k] = -a0; nqy[k] = -a1; nqz[k] = -a2;
        q2[k]  = a0 * a0 + a1 * a1 + a2 * a2;
        best[k] = FLT_MAX;
    }

    // Wave-uniform ref chunk -> scalar loads; 36 VALU instrs per ref point.
    const float* __restrict__ rp =
        r + ((size_t)b * N_ + (size_t)jc * CHUNK) * 3;

    #pragma unroll 4
    for (int j = 0; j < CHUNK; ++j) {
        const float sx = rp[3 * j + 0];
        const float sy = rp[3 * j + 1];
        const float sz = rp[3 * j + 2];
        const float r2h = 0.5f * (sx * sx + sy * sy + sz * sz);
        #pragma unroll
        for (int k = 0; k < QPT; ++k) {
            float acc = fmaf(nqx[k], sx, r2h);
            acc = fmaf(nqy[k], sy, acc);
            acc = fmaf(nqz[k], sz, acc);
            best[k] = fminf(best[k], acc);
        }
    }

    float* op = partial + (((size_t)dir * B_ + b) * NJC + jc) * N_ + i0;
    #pragma unroll
    for (int k = 0; k < QPT; ++k)
        op[k] = 2.0f * best[k] + q2[k];
}

__global__ __launch_bounds__(THREADS)
void cd_reduce_kernel(const float* __restrict__ partial,
                      float* __restrict__ out, int njc) {
    const int b = blockIdx.x;
    const int t = (int)threadIdx.x;

    float sum = 0.0f;
    for (int dir = 0; dir < 2; ++dir) {
        const float* __restrict__ p =
            partial + ((size_t)dir * B_ + b) * (size_t)njc * N_;
        for (int i = t; i < N_; i += THREADS) {
            float m = p[i];
            for (int c = 1; c < njc; ++c)
                m = fminf(m, p[(size_t)c * N_ + i]);
            sum += m;
        }
    }

    #pragma unroll
    for (int o = 32; o > 0; o >>= 1)
        sum += __shfl_down(sum, o, 64);

    __shared__ float red[THREADS / 64];
    if ((t & 63) == 0) red[t >> 6] = sum;
    __syncthreads();
    if (t == 0) {
        float tot = 0.0f;
        #pragma unroll
        for (int w = 0; w < THREADS / 64; ++w) tot += red[w];
        out[b] = tot * (1.0f / (float)N_);
    }
}

extern "C" void kernel_launch(void* const* d_in, const int* in_sizes, int n_in,
                              void* d_out, int out_size, void* d_ws, size_t ws_size,
                              hipStream_t stream) {
    const float* x = (const float*)d_in[0];
    const float* y = (const float*)d_in[1];
    float* out     = (float*)d_out;
    float* partial = (float*)d_ws;

    const size_t need16 = 2ull * B_ * 16 * N_ * sizeof(float);  // 4 MiB
    if (ws_size >= need16) {
        dim3 grid(16, B_, 2);   // 512 blocks -> 2 blocks/CU, 2 waves/SIMD
        cd_min_kernel<16><<<grid, dim3(THREADS), 0, stream>>>(x, y, partial);
        cd_reduce_kernel<<<dim3(B_), dim3(THREADS), 0, stream>>>(partial, out, 16);
    } else {
        dim3 grid(8, B_, 2);    // 256 blocks -> 1 block/CU
        cd_min_kernel<8><<<grid, dim3(THREADS), 0, stream>>>(x, y, partial);
        cd_reduce_kernel<<<dim3(B_), dim3(THREADS), 0, stream>>>(partial, out, 8);
    }
}

// Round 3
// 32.597 us; speedup vs baseline: 2.8829x; 2.2315x over previous
//
#include <hip/hip_runtime.h>
#include <float.h>

// Chamfer distance, B=16, N=2048, D=3, fp32.
// cd[b] = mean_j min_i |x_i - y_j|^2 + mean_i min_j |x_i - y_j|^2
// Pair form: |q - r|^2 = 2*(0.5|r|^2 - q.r) + |q|^2.

constexpr int B_ = 16;
constexpr int N_ = 2048;
constexpr int THREADS = 256;
constexpr int QPT = 8;                  // queries per thread; THREADS*QPT == N_
constexpr int SLICES = N_ / THREADS;    // 8 combine slices per (dir,b)

// ws layout: float partial[2][B_][NJC][N_], then float sums[2][B_][SLICES]

template <int NJC>
__global__ __launch_bounds__(THREADS)
void cd_min_kernel(const float* __restrict__ x,
                   const float* __restrict__ y,
                   float* __restrict__ partial) {
    constexpr int CHUNK = N_ / NJC;
    const int jc  = blockIdx.x;
    const int b   = blockIdx.y;
    const int dir = blockIdx.z;

    const float* __restrict__ q = dir ? y : x;
    const float* __restrict__ r = dir ? x : y;

    const int i0 = (int)threadIdx.x * QPT;
    const float* qp = q + ((size_t)b * N_ + i0) * 3;

    float nqx[QPT], nqy[QPT], nqz[QPT], q2[QPT], best[QPT];
    #pragma unroll
    for (int k = 0; k < QPT; ++k) {
        const float a0 = qp[3 * k + 0];
        const float a1 = qp[3 * k + 1];
        const float a2 = qp[3 * k + 2];
        nqx[k] = -a0; nqy[k] = -a1; nqz[k] = -a2;
        q2[k]  = a0 * a0 + a1 * a1 + a2 * a2;
        best[k] = FLT_MAX;
    }

    // Wave-uniform ref chunk -> scalar loads; 36 VALU instrs per ref point
    // amortized over 8 independent min chains.
    const float* __restrict__ rp =
        r + ((size_t)b * N_ + (size_t)jc * CHUNK) * 3;

    #pragma unroll 4
    for (int j = 0; j < CHUNK; ++j) {
        const float sx = rp[3 * j + 0];
        const float sy = rp[3 * j + 1];
        const float sz = rp[3 * j + 2];
        const float r2h = 0.5f * (sx * sx + sy * sy + sz * sz);
        #pragma unroll
        for (int k = 0; k < QPT; ++k) {
            float acc = fmaf(nqx[k], sx, r2h);
            acc = fmaf(nqy[k], sy, acc);
            acc = fmaf(nqz[k], sz, acc);
            best[k] = fminf(best[k], acc);
        }
    }

    float* op = partial + (((size_t)dir * B_ + b) * NJC + jc) * N_ + i0;
    #pragma unroll
    for (int k = 0; k < QPT; ++k)
        op[k] = 2.0f * best[k] + q2[k];
}

// Stage 2: grid (B_, 2, SLICES). Each block: min over NJC chunks for its 256
// queries, then block-sum -> sums[dir][b][slice].
__global__ __launch_bounds__(THREADS)
void cd_combine_kernel(const float* __restrict__ partial,
                       float* __restrict__ sums, int njc) {
    const int b     = blockIdx.x;
    const int dir   = blockIdx.y;
    const int slice = blockIdx.z;
    const int t     = (int)threadIdx.x;
    const int i     = slice * THREADS + t;

    const float* __restrict__ p =
        partial + ((size_t)dir * B_ + b) * (size_t)njc * N_ + i;

    float m = FLT_MAX;
    for (int c = 0; c < njc; ++c)
        m = fminf(m, p[(size_t)c * N_]);

    float s = m;
    #pragma unroll
    for (int o = 32; o > 0; o >>= 1)
        s += __shfl_down(s, o, 64);

    __shared__ float red[THREADS / 64];
    if ((t & 63) == 0) red[t >> 6] = s;
    __syncthreads();
    if (t == 0) {
        float tot = 0.0f;
        #pragma unroll
        for (int w = 0; w < THREADS / 64; ++w) tot += red[w];
        sums[((size_t)dir * B_ + b) * SLICES + slice] = tot;
    }
}

// Stage 3: one block. Thread t -> b = t/16, k = t%16 -> (dir, slice).
// Width-16 shuffle reduce, lane 0 of each group writes out[b].
__global__ __launch_bounds__(THREADS)
void cd_final_kernel(const float* __restrict__ sums,
                     float* __restrict__ out) {
    const int t   = (int)threadIdx.x;
    const int b   = t >> 4;
    const int k   = t & 15;
    const int dir = k >> 3;
    const int sl  = k & 7;

    float v = sums[((size_t)dir * B_ + b) * SLICES + sl];
    v += __shfl_down(v, 8, 16);
    v += __shfl_down(v, 4, 16);
    v += __shfl_down(v, 2, 16);
    v += __shfl_down(v, 1, 16);
    if (k == 0) out[b] = v * (1.0f / (float)N_);
}

extern "C" void kernel_launch(void* const* d_in, const int* in_sizes, int n_in,
                              void* d_out, int out_size, void* d_ws, size_t ws_size,
                              hipStream_t stream) {
    const float* x = (const float*)d_in[0];
    const float* y = (const float*)d_in[1];
    float* out     = (float*)d_out;
    float* partial = (float*)d_ws;

    auto need = [](int njc) -> size_t {
        return 2ull * B_ * njc * N_ * sizeof(float)
             + 2ull * B_ * SLICES * sizeof(float);
    };

    int njc;
    if      (ws_size >= need(32)) njc = 32;
    else if (ws_size >= need(16)) njc = 16;
    else                          njc = 8;

    float* sums = partial + 2ull * B_ * njc * N_;

    dim3 gmin(njc, B_, 2);
    if (njc == 32)
        cd_min_kernel<32><<<gmin, dim3(THREADS), 0, stream>>>(x, y, partial);
    else if (njc == 16)
        cd_min_kernel<16><<<gmin, dim3(THREADS), 0, stream>>>(x, y, partial);
    else
        cd_min_kernel<8><<<gmin, dim3(THREADS), 0, stream>>>(x, y, partial);

    cd_combine_kernel<<<dim3(B_, 2, SLICES), dim3(THREADS), 0, stream>>>(
        partial, sums, njc);
    cd_final_kernel<<<dim3(1), dim3(THREADS), 0, stream>>>(sums, out);
}

// Round 4
// 30.053 us; speedup vs baseline: 3.1269x; 1.0846x over previous
//
#include <hip/hip_runtime.h>
#include <float.h>

// Chamfer distance, B=16, N=2048, D=3, fp32.
// cd[b] = mean_j min_i |x_i - y_j|^2 + mean_i min_j |x_i - y_j|^2
// Pair form: |q - r|^2 = 2*(0.5|r|^2 - q.r) + |q|^2.
// VALU packing: queries paired into float2 -> v_pk_fma_f32; ref loop
// unrolled x2 with nested fmin -> v_min3_f32. ~1.75 VALU instr/pair.

constexpr int B_ = 16;
constexpr int N_ = 2048;
constexpr int THREADS = 256;
constexpr int QPT = 8;                  // queries per thread; THREADS*QPT == N_
constexpr int QP2 = QPT / 2;            // float2 pairs
constexpr int SLICES = N_ / THREADS;    // 8 combine slices per (dir,b)

typedef float v2f __attribute__((ext_vector_type(2)));

// ws layout: float partial[2][B_][NJC][N_], then float sums[2][B_][SLICES]

template <int NJC>
__global__ __launch_bounds__(THREADS)
void cd_min_kernel(const float* __restrict__ x,
                   const float* __restrict__ y,
                   float* __restrict__ partial) {
    constexpr int CHUNK = N_ / NJC;
    const int jc  = blockIdx.x;
    const int b   = blockIdx.y;
    const int dir = blockIdx.z;

    const float* __restrict__ q = dir ? y : x;
    const float* __restrict__ r = dir ? x : y;

    const int i0 = (int)threadIdx.x * QPT;
    const float* qp = q + ((size_t)b * N_ + i0) * 3;

    v2f nqx[QP2], nqy[QP2], nqz[QP2], q2[QP2], best[QP2];
    #pragma unroll
    for (int k = 0; k < QP2; ++k) {
        const float a0 = qp[6 * k + 0], a1 = qp[6 * k + 1], a2 = qp[6 * k + 2];
        const float b0 = qp[6 * k + 3], b1 = qp[6 * k + 4], b2 = qp[6 * k + 5];
        nqx[k] = (v2f){-a0, -b0};
        nqy[k] = (v2f){-a1, -b1};
        nqz[k] = (v2f){-a2, -b2};
        q2[k]  = (v2f){a0 * a0 + a1 * a1 + a2 * a2,
                       b0 * b0 + b1 * b1 + b2 * b2};
        best[k] = (v2f){FLT_MAX, FLT_MAX};
    }

    // Wave-uniform ref chunk -> scalar loads.
    const float* __restrict__ rp =
        r + ((size_t)b * N_ + (size_t)jc * CHUNK) * 3;

    #pragma unroll 2
    for (int j = 0; j < CHUNK; j += 2) {
        const float sx0 = rp[3 * j + 0], sy0 = rp[3 * j + 1], sz0 = rp[3 * j + 2];
        const float sx1 = rp[3 * j + 3], sy1 = rp[3 * j + 4], sz1 = rp[3 * j + 5];
        const float h0 = 0.5f * (sx0 * sx0 + sy0 * sy0 + sz0 * sz0);
        const float h1 = 0.5f * (sx1 * sx1 + sy1 * sy1 + sz1 * sz1);
        const v2f X0 = (v2f){sx0, sx0}, Y0 = (v2f){sy0, sy0}, Z0 = (v2f){sz0, sz0};
        const v2f X1 = (v2f){sx1, sx1}, Y1 = (v2f){sy1, sy1}, Z1 = (v2f){sz1, sz1};
        const v2f H0 = (v2f){h0, h0},   H1 = (v2f){h1, h1};
        #pragma unroll
        for (int k = 0; k < QP2; ++k) {
            v2f a = __builtin_elementwise_fma(nqx[k], X0, H0);
            a = __builtin_elementwise_fma(nqy[k], Y0, a);
            a = __builtin_elementwise_fma(nqz[k], Z0, a);
            v2f c = __builtin_elementwise_fma(nqx[k], X1, H1);
            c = __builtin_elementwise_fma(nqy[k], Y1, c);
            c = __builtin_elementwise_fma(nqz[k], Z1, c);
            // min3 fusion: min(best, min(a, c))
            best[k] = __builtin_elementwise_min(
                best[k], __builtin_elementwise_min(a, c));
        }
    }

    float res[QPT];
    #pragma unroll
    for (int k = 0; k < QP2; ++k) {
        res[2 * k + 0] = 2.0f * best[k].x + q2[k].x;
        res[2 * k + 1] = 2.0f * best[k].y + q2[k].y;
    }
    float4* op = (float4*)(partial
        + (((size_t)dir * B_ + b) * NJC + jc) * N_ + i0);
    op[0] = *(float4*)&res[0];
    op[1] = *(float4*)&res[4];
}

// Stage 2: grid (B_, 2, SLICES). Each block: min over NJC chunks for its 256
// queries, then block-sum -> sums[dir][b][slice].
__global__ __launch_bounds__(THREADS)
void cd_combine_kernel(const float* __restrict__ partial,
                       float* __restrict__ sums, int njc) {
    const int b     = blockIdx.x;
    const int dir   = blockIdx.y;
    const int slice = blockIdx.z;
    const int t     = (int)threadIdx.x;
    const int i     = slice * THREADS + t;

    const float* __restrict__ p =
        partial + ((size_t)dir * B_ + b) * (size_t)njc * N_ + i;

    float m = FLT_MAX;
    for (int c = 0; c < njc; ++c)
        m = fminf(m, p[(size_t)c * N_]);

    float s = m;
    #pragma unroll
    for (int o = 32; o > 0; o >>= 1)
        s += __shfl_down(s, o, 64);

    __shared__ float red[THREADS / 64];
    if ((t & 63) == 0) red[t >> 6] = s;
    __syncthreads();
    if (t == 0) {
        float tot = 0.0f;
        #pragma unroll
        for (int w = 0; w < THREADS / 64; ++w) tot += red[w];
        sums[((size_t)dir * B_ + b) * SLICES + slice] = tot;
    }
}

// Stage 3: one block. Thread t -> b = t/16, k = t%16 -> (dir, slice).
__global__ __launch_bounds__(THREADS)
void cd_final_kernel(const float* __restrict__ sums,
                     float* __restrict__ out) {
    const int t   = (int)threadIdx.x;
    const int b   = t >> 4;
    const int k   = t & 15;
    const int dir = k >> 3;
    const int sl  = k & 7;

    float v = sums[((size_t)dir * B_ + b) * SLICES + sl];
    v += __shfl_down(v, 8, 16);
    v += __shfl_down(v, 4, 16);
    v += __shfl_down(v, 2, 16);
    v += __shfl_down(v, 1, 16);
    if (k == 0) out[b] = v * (1.0f / (float)N_);
}

extern "C" void kernel_launch(void* const* d_in, const int* in_sizes, int n_in,
                              void* d_out, int out_size, void* d_ws, size_t ws_size,
                              hipStream_t stream) {
    const float* x = (const float*)d_in[0];
    const float* y = (const float*)d_in[1];
    float* out     = (float*)d_out;
    float* partial = (float*)d_ws;

    auto need = [](int njc) -> size_t {
        return 2ull * B_ * njc * N_ * sizeof(float)
             + 2ull * B_ * SLICES * sizeof(float);
    };

    int njc;
    if      (ws_size >= need(32)) njc = 32;
    else if (ws_size >= need(16)) njc = 16;
    else                          njc = 8;

    float* sums = partial + 2ull * B_ * njc * N_;

    dim3 gmin(njc, B_, 2);
    if (njc == 32)
        cd_min_kernel<32><<<gmin, dim3(THREADS), 0, stream>>>(x, y, partial);
    else if (njc == 16)
        cd_min_kernel<16><<<gmin, dim3(THREADS), 0, stream>>>(x, y, partial);
    else
        cd_min_kernel<8><<<gmin, dim3(THREADS), 0, stream>>>(x, y, partial);

    cd_combine_kernel<<<dim3(B_, 2, SLICES), dim3(THREADS), 0, stream>>>(
        partial, sums, njc);
    cd_final_kernel<<<dim3(1), dim3(THREADS), 0, stream>>>(sums, out);
}

// Round 5
// 24.612 us; speedup vs baseline: 3.8181x; 1.2211x over previous
//
#include <hip/hip_runtime.h>
#include <float.h>

// Chamfer distance, B=16, N=2048, D=3, fp32.
// cd[b] = mean_j min_i |x_i - y_j|^2 + mean_i min_j |x_i - y_j|^2
// Pair form: |q - r|^2 = 2*(0.5|r|^2 - q.r) + |q|^2.
// Ref points staged in LDS (SoA + precomputed 0.5|r|^2): wave-uniform
// ds_read broadcast pipelines (in-order lgkmcnt), unlike s_load which
// forces lgkmcnt(0) drains. Math packed into v_pk_fma_f32 + min3.

constexpr int B_ = 16;
constexpr int N_ = 2048;
constexpr int THREADS = 256;
constexpr int QPT = 8;                  // queries per thread; THREADS*QPT == N_
constexpr int QP2 = QPT / 2;            // float2 pairs
constexpr int SLICES = N_ / THREADS;    // 8 combine slices per (dir,b)

typedef float v2f __attribute__((ext_vector_type(2)));

// ws layout: float partial[2][B_][NJC][N_], then float sums[2][B_][SLICES]

template <int NJC>
__global__ __launch_bounds__(THREADS)
void cd_min_kernel(const float* __restrict__ x,
                   const float* __restrict__ y,
                   float* __restrict__ partial) {
    constexpr int CHUNK = N_ / NJC;     // 64 for NJC=32
    const int jc  = blockIdx.x;
    const int b   = blockIdx.y;
    const int dir = blockIdx.z;

    const float* __restrict__ q = dir ? y : x;
    const float* __restrict__ r = dir ? x : y;

    // ---- stage ref chunk into LDS, SoA + half-norm row ----
    __shared__ float lref[4][CHUNK];    // [x|y|z|0.5*|r|^2][point]
    {
        const float* __restrict__ rp =
            r + ((size_t)b * N_ + (size_t)jc * CHUNK) * 3;
        for (int p = (int)threadIdx.x; p < CHUNK; p += THREADS) {
            const float rx = rp[3 * p + 0];
            const float ry = rp[3 * p + 1];
            const float rz = rp[3 * p + 2];
            lref[0][p] = rx;
            lref[1][p] = ry;
            lref[2][p] = rz;
            lref[3][p] = 0.5f * (rx * rx + ry * ry + rz * rz);
        }
    }

    // ---- per-thread query registers ----
    const int i0 = (int)threadIdx.x * QPT;
    const float* qp = q + ((size_t)b * N_ + i0) * 3;

    v2f nqx[QP2], nqy[QP2], nqz[QP2], q2[QP2], best[QP2];
    #pragma unroll
    for (int k = 0; k < QP2; ++k) {
        const float a0 = qp[6 * k + 0], a1 = qp[6 * k + 1], a2 = qp[6 * k + 2];
        const float b0 = qp[6 * k + 3], b1 = qp[6 * k + 4], b2 = qp[6 * k + 5];
        nqx[k] = (v2f){-a0, -b0};
        nqy[k] = (v2f){-a1, -b1};
        nqz[k] = (v2f){-a2, -b2};
        q2[k]  = (v2f){a0 * a0 + a1 * a1 + a2 * a2,
                       b0 * b0 + b1 * b1 + b2 * b2};
        best[k] = (v2f){FLT_MAX, FLT_MAX};
    }
    __syncthreads();

    // ---- main loop: 2 refs per iter, uniform LDS broadcast reads ----
    const v2f* __restrict__ lx = (const v2f*)lref[0];
    const v2f* __restrict__ ly = (const v2f*)lref[1];
    const v2f* __restrict__ lz = (const v2f*)lref[2];
    const v2f* __restrict__ lh = (const v2f*)lref[3];

    #pragma unroll 4
    for (int j2 = 0; j2 < CHUNK / 2; ++j2) {
        const v2f sx = lx[j2], sy = ly[j2], sz = lz[j2], sh = lh[j2];
        const v2f X0 = (v2f){sx.x, sx.x}, X1 = (v2f){sx.y, sx.y};
        const v2f Y0 = (v2f){sy.x, sy.x}, Y1 = (v2f){sy.y, sy.y};
        const v2f Z0 = (v2f){sz.x, sz.x}, Z1 = (v2f){sz.y, sz.y};
        const v2f H0 = (v2f){sh.x, sh.x}, H1 = (v2f){sh.y, sh.y};
        #pragma unroll
        for (int k = 0; k < QP2; ++k) {
            v2f a = __builtin_elementwise_fma(nqx[k], X0, H0);
            a = __builtin_elementwise_fma(nqy[k], Y0, a);
            a = __builtin_elementwise_fma(nqz[k], Z0, a);
            v2f c = __builtin_elementwise_fma(nqx[k], X1, H1);
            c = __builtin_elementwise_fma(nqy[k], Y1, c);
            c = __builtin_elementwise_fma(nqz[k], Z1, c);
            best[k] = __builtin_elementwise_min(
                best[k], __builtin_elementwise_min(a, c));
        }
    }

    float res[QPT];
    #pragma unroll
    for (int k = 0; k < QP2; ++k) {
        res[2 * k + 0] = 2.0f * best[k].x + q2[k].x;
        res[2 * k + 1] = 2.0f * best[k].y + q2[k].y;
    }
    float4* op = (float4*)(partial
        + (((size_t)dir * B_ + b) * NJC + jc) * N_ + i0);
    op[0] = *(float4*)&res[0];
    op[1] = *(float4*)&res[4];
}

// Stage 2: grid (B_, 2, SLICES). Min over NJC chunks (fully unrolled ->
// batched vmcnt loads, no dependent load+min chain), then block-sum.
template <int NJC>
__global__ __launch_bounds__(THREADS)
void cd_combine_kernel(const float* __restrict__ partial,
                       float* __restrict__ sums) {
    const int b     = blockIdx.x;
    const int dir   = blockIdx.y;
    const int slice = blockIdx.z;
    const int t     = (int)threadIdx.x;
    const int i     = slice * THREADS + t;

    const float* __restrict__ p =
        partial + ((size_t)dir * B_ + b) * (size_t)NJC * N_ + i;

    float m = FLT_MAX;
    #pragma unroll
    for (int c = 0; c < NJC; ++c)
        m = fminf(m, p[(size_t)c * N_]);

    float s = m;
    #pragma unroll
    for (int o = 32; o > 0; o >>= 1)
        s += __shfl_down(s, o, 64);

    __shared__ float red[THREADS / 64];
    if ((t & 63) == 0) red[t >> 6] = s;
    __syncthreads();
    if (t == 0) {
        float tot = 0.0f;
        #pragma unroll
        for (int w = 0; w < THREADS / 64; ++w) tot += red[w];
        sums[((size_t)dir * B_ + b) * SLICES + slice] = tot;
    }
}

// Stage 3: one block. Thread t -> b = t/16, k = t%16 -> (dir, slice).
__global__ __launch_bounds__(THREADS)
void cd_final_kernel(const float* __restrict__ sums,
                     float* __restrict__ out) {
    const int t   = (int)threadIdx.x;
    const int b   = t >> 4;
    const int k   = t & 15;
    const int dir = k >> 3;
    const int sl  = k & 7;

    float v = sums[((size_t)dir * B_ + b) * SLICES + sl];
    v += __shfl_down(v, 8, 16);
    v += __shfl_down(v, 4, 16);
    v += __shfl_down(v, 2, 16);
    v += __shfl_down(v, 1, 16);
    if (k == 0) out[b] = v * (1.0f / (float)N_);
}

extern "C" void kernel_launch(void* const* d_in, const int* in_sizes, int n_in,
                              void* d_out, int out_size, void* d_ws, size_t ws_size,
                              hipStream_t stream) {
    const float* x = (const float*)d_in[0];
    const float* y = (const float*)d_in[1];
    float* out     = (float*)d_out;
    float* partial = (float*)d_ws;

    auto need = [](int njc) -> size_t {
        return 2ull * B_ * njc * N_ * sizeof(float)
             + 2ull * B_ * SLICES * sizeof(float);
    };

    const dim3 gcomb(B_, 2, SLICES);
    if (ws_size >= need(32)) {
        float* sums = partial + 2ull * B_ * 32 * N_;
        cd_min_kernel<32><<<dim3(32, B_, 2), dim3(THREADS), 0, stream>>>(x, y, partial);
        cd_combine_kernel<32><<<gcomb, dim3(THREADS), 0, stream>>>(partial, sums);
        cd_final_kernel<<<dim3(1), dim3(THREADS), 0, stream>>>(sums, out);
    } else if (ws_size >= need(16)) {
        float* sums = partial + 2ull * B_ * 16 * N_;
        cd_min_kernel<16><<<dim3(16, B_, 2), dim3(THREADS), 0, stream>>>(x, y, partial);
        cd_combine_kernel<16><<<gcomb, dim3(THREADS), 0, stream>>>(partial, sums);
        cd_final_kernel<<<dim3(1), dim3(THREADS), 0, stream>>>(sums, out);
    } else {
        float* sums = partial + 2ull * B_ * 8 * N_;
        cd_min_kernel<8><<<dim3(8, B_, 2), dim3(THREADS), 0, stream>>>(x, y, partial);
        cd_combine_kernel<8><<<gcomb, dim3(THREADS), 0, stream>>>(partial, sums);
        cd_final_kernel<<<dim3(1), dim3(THREADS), 0, stream>>>(sums, out);
    }
}